// Round 11
// baseline (720.538 us; speedup 1.0000x reference)
//
#include <hip/hip_runtime.h>

#define T_ 512
#define K_ 128
#define B_ 256
// skewed state layout: value i lives at dword ((i>>5)*36 + (i&31));
// 4 row-blocks of 32 dwords at bases {0,36,72,108} -> base mod 32 =
// {0,4,8,12}: the 4 broadcast addresses of each read inst hit disjoint
// bank quads -> zero conflicts.
#define SKW(i) ((((i) >> 5) * 36) + ((i) & 31))

// Role-split grid: blocks [0,256) = forward, blocks [256,512) = viterbi.
// History: 697 (R5, fused 8-wave) -> 548 (R8, role-split) -> 494.6 (R10,
// bank-skew + tournament; conflicts 0, DS-pipe-bound: ~1700 of 2323
// cyc/step is LDS b128 broadcast traffic).
// R11: columns-per-thread C=2 (thread g=tid>>2 owns cols {2g,2g+1},
// rg=tid&3 owns rows [32rg,32rg+32)). Per-thread b128 reads halve (16->8),
// amortized over 2 columns; combine = shfl_xor 1,2 (rg = lane bits [1:0]).

__global__ __launch_bounds__(256, 2) void crf_main(
    const float* __restrict__ emissions,
    const int* __restrict__ tag_ids,
    const int* __restrict__ lengths,
    const float* __restrict__ transitions,
    float* __restrict__ out,
    float* __restrict__ ws_ll,
    int* __restrict__ ws_cnt)
{
    const int bid = blockIdx.x;
    const int tid = threadIdx.x;

    const int g  = tid >> 2;          // column-pair 0..63
    const int rg = tid & 3;           // row quarter
    const int j0 = 2 * g;             // first owned column
    const int wiA = (g >> 4) * 36 + 2 * (g & 15);   // = SKW(j0); j0 even

    if (bid < B_) {
        // ==================== FORWARD block ====================
        __shared__ __align__(16) float eaBuf[2][4 * 36];   // exp(alpha-S), skewed dbuf
        __shared__ __align__(16) float wmax[4];            // per-wave max of alpha
        __shared__ float redLDS[4];                        // score partials

        const int b   = bid;
        const int len = lengths[b];
        const float* emB = emissions + (size_t)b * T_ * K_;
        const int*  tagB = tag_ids + b * T_;

        // ---- sequence score (unary + binary), 2 t per thread ----
        {
            float s = 0.f;
            #pragma unroll
            for (int h = 0; h < 2; ++h) {
                int t = tid + h * 256;
                if (t < len) {
                    int tg = tagB[t];
                    float v = emB[t * K_ + tg];
                    if (t >= 1) v += transitions[tagB[t - 1] * K_ + tg];
                    s += v;
                }
            }
            #pragma unroll
            for (int m = 1; m < 64; m <<= 1) s += __shfl_xor(s, m);
            if ((tid & 63) == 0) redLDS[tid >> 6] = s;
        }

        // tbl[2k+cc] = exp(T[rg*32+k][j0+cc]), k<32, cc<2
        float tbl[64];
        #pragma unroll
        for (int k = 0; k < 32; ++k) {
            float2 tr = *(const float2*)&transitions[(rg * 32 + k) * K_ + j0];
            tbl[2 * k + 0] = __expf(tr.x);
            tbl[2 * k + 1] = __expf(tr.y);
        }

        // ---- init t = 0 (offset S0 = 0) ----
        {
            float2 e0 = *(const float2*)(emB + j0);
            if (rg == 0) {
                float2 w2; w2.x = __expf(e0.x); w2.y = __expf(e0.y);
                *(float2*)&eaBuf[0][wiA] = w2;
            }
            float wm = fmaxf(e0.x, e0.y);
            #pragma unroll
            for (int m = 1; m < 64; m <<= 1) wm = fmaxf(wm, __shfl_xor(wm, m));
            if ((tid & 63) == 0) wmax[tid >> 6] = wm;
        }
        __syncthreads();

        int cur = 0;
        float Sr = 0.f;                                // scale of current ea buffer
        float2 emN = *(const float2*)(emB + K_ + j0);  // prefetch t = 1

        for (int t = 1; t < len; ++t) {
            float2 emC = emN;
            int tn = (t + 1 < T_) ? (t + 1) : t;
            emN = *(const float2*)(emB + tn * K_ + j0);

            float Sw;
            if (((t - 1) & 3) == 0) {                  // window start: fresh scale
                float4 wv = *(const float4*)&wmax[0];
                Sw = fmaxf(fmaxf(wv.x, wv.y), fmaxf(wv.z, wv.w));
            } else Sw = Sr;

            const float* ea = &eaBuf[cur][rg * 36];
            float a00 = 0.f, a01 = 0.f, a02 = 0.f, a03 = 0.f;
            float a10 = 0.f, a11 = 0.f, a12 = 0.f, a13 = 0.f;
            #pragma unroll
            for (int m = 0; m < 8; ++m) {
                float4 e4 = *(const float4*)(ea + 4 * m);
                a00 = fmaf(e4.x, tbl[8 * m + 0], a00);
                a10 = fmaf(e4.x, tbl[8 * m + 1], a10);
                a01 = fmaf(e4.y, tbl[8 * m + 2], a01);
                a11 = fmaf(e4.y, tbl[8 * m + 3], a11);
                a02 = fmaf(e4.z, tbl[8 * m + 4], a02);
                a12 = fmaf(e4.z, tbl[8 * m + 5], a12);
                a03 = fmaf(e4.w, tbl[8 * m + 6], a03);
                a13 = fmaf(e4.w, tbl[8 * m + 7], a13);
            }
            float d0 = (a00 + a01) + (a02 + a03);
            float d1 = (a10 + a11) + (a12 + a13);
            d0 += __shfl_xor(d0, 1); d0 += __shfl_xor(d0, 2);   // sum over rg
            d1 += __shfl_xor(d1, 1); d1 += __shfl_xor(d1, 2);

            float an0 = __logf(d0) + Sr + emC.x;
            float an1 = __logf(d1) + Sr + emC.y;
            if (rg == 0) {
                float2 w2; w2.x = __expf(an0 - Sw); w2.y = __expf(an1 - Sw);
                *(float2*)&eaBuf[cur ^ 1][wiA] = w2;
            }
            Sr = Sw;

            if (((t - 1) & 3) == 3) {                  // window end: publish max
                float wm = fmaxf(an0, an1);
                #pragma unroll
                for (int m = 1; m < 64; m <<= 1) wm = fmaxf(wm, __shfl_xor(wm, m));
                if ((tid & 63) == 0) wmax[tid >> 6] = wm;
            }
            cur ^= 1;
            __syncthreads();
        }

        // ---- logZ + final write ----
        float logZv = 0.f;
        if (tid < 64) {
            float s = eaBuf[cur][SKW(tid)] + eaBuf[cur][SKW(tid + 64)];
            #pragma unroll
            for (int m = 1; m < 64; m <<= 1) s += __shfl_xor(s, m);
            logZv = Sr + __logf(s);                    // valid in tid 0
        }
        if (tid == 0) {
            float sc = redLDS[0] + redLDS[1] + redLDS[2] + redLDS[3];
            ws_ll[b] = sc - logZv;
        }

    } else {
        // ==================== VITERBI block ====================
        __shared__ unsigned char bpLDS[T_ * K_];           // 64 KB backpointers
        __shared__ __align__(16) float vaBuf[2][4 * 36];   // skewed dbuf
        __shared__ unsigned char decLDS[T_];               // decoded chain
        __shared__ int redILDS[4];                         // accuracy partials
        __shared__ int ltagLDS;

        const int b   = bid - B_;
        const int len = lengths[b];
        const float* emB = emissions + (size_t)b * T_ * K_;
        const int*  tagB = tag_ids + b * T_;

        float tbl[64];
        #pragma unroll
        for (int k = 0; k < 32; ++k) {
            float2 tr = *(const float2*)&transitions[(rg * 32 + k) * K_ + j0];
            tbl[2 * k + 0] = tr.x;
            tbl[2 * k + 1] = tr.y;
        }

        // ---- init t = 0 ----
        {
            float2 e0 = *(const float2*)(emB + j0);
            if (rg == 0) *(float2*)&vaBuf[0][wiA] = e0;
        }
        __syncthreads();

        int cur = 0;
        float2 emN = *(const float2*)(emB + K_ + j0);  // prefetch t = 1

        for (int t = 1; t < len; ++t) {
            float2 emC = emN;
            int tn = (t + 1 < T_) ? (t + 1) : t;
            emN = *(const float2*)(emB + tn * K_ + j0);

            const float* va = &vaBuf[cur][rg * 36];
            // per-column tournament over this thread's 32 rows
            // (first-max-wins at every level), then (val, global idx)
            // combine across the 4 rgs.
            float v0[8], v1[8];
            int   g0[8], g1[8];
            #pragma unroll
            for (int m = 0; m < 8; ++m) {
                float4 e4 = *(const float4*)(va + 4 * m);
                // column 0
                float s0 = e4.x + tbl[8 * m + 0];
                float s1 = e4.y + tbl[8 * m + 2];
                float s2 = e4.z + tbl[8 * m + 4];
                float s3 = e4.w + tbl[8 * m + 6];
                float mA; int aA;
                if (s1 > s0) { mA = s1; aA = 4 * m + 1; } else { mA = s0; aA = 4 * m + 0; }
                float mC; int aC;
                if (s3 > s2) { mC = s3; aC = 4 * m + 3; } else { mC = s2; aC = 4 * m + 2; }
                if (mC > mA) { v0[m] = mC; g0[m] = aC; } else { v0[m] = mA; g0[m] = aA; }
                // column 1
                float u0 = e4.x + tbl[8 * m + 1];
                float u1 = e4.y + tbl[8 * m + 3];
                float u2 = e4.z + tbl[8 * m + 5];
                float u3 = e4.w + tbl[8 * m + 7];
                float nA; int bA;
                if (u1 > u0) { nA = u1; bA = 4 * m + 1; } else { nA = u0; bA = 4 * m + 0; }
                float nC; int bC;
                if (u3 > u2) { nC = u3; bC = 4 * m + 3; } else { nC = u2; bC = 4 * m + 2; }
                if (nC > nA) { v1[m] = nC; g1[m] = bC; } else { v1[m] = nA; g1[m] = bA; }
            }
            #pragma unroll
            for (int st = 1; st < 8; st <<= 1) {
                #pragma unroll
                for (int k = 0; k < 8; k += 2 * st) {
                    if (v0[k + st] > v0[k]) { v0[k] = v0[k + st]; g0[k] = g0[k + st]; }
                    if (v1[k + st] > v1[k]) { v1[k] = v1[k + st]; g1[k] = g1[k + st]; }
                }
            }
            float m0 = v0[0];  int a0i = g0[0] + rg * 32;   // global row idx
            float m1 = v1[0];  int a1i = g1[0] + rg * 32;

            // combine across rgs (lane bits [1:0]); explicit idx compare ->
            // lowest-global-index-among-maxima, order-independent.
            #pragma unroll
            for (int sft = 1; sft <= 2; sft <<= 1) {
                float o0 = __shfl_xor(m0, sft); int b0 = __shfl_xor(a0i, sft);
                if (o0 > m0 || (o0 == m0 && b0 < a0i)) { m0 = o0; a0i = b0; }
                float o1 = __shfl_xor(m1, sft); int b1 = __shfl_xor(a1i, sft);
                if (o1 > m1 || (o1 == m1 && b1 < a1i)) { m1 = o1; a1i = b1; }
            }
            if (rg == 0) {
                float2 nv; nv.x = m0 + emC.x; nv.y = m1 + emC.y;
                *(float2*)&vaBuf[cur ^ 1][wiA] = nv;
                *(unsigned short*)&bpLDS[t * K_ + j0] =
                    (unsigned short)((a0i & 0xff) | ((a1i & 0xff) << 8));
            }
            cur ^= 1;
            __syncthreads();
        }

        // ---- last tag: argmax_j v_final (first-max-wins) ----
        if (tid < 64) {
            int l = tid;
            float m = vaBuf[cur][SKW(l)]; int a = l;
            float v2 = vaBuf[cur][SKW(l + 64)];
            if (v2 > m) { m = v2; a = l + 64; }
            #pragma unroll
            for (int sft = 1; sft < 64; sft <<= 1) {
                float om = __shfl_xor(m, sft);
                int   oa = __shfl_xor(a, sft);
                if (om > m || (om == m && oa < a)) { m = om; a = oa; }
            }
            if (l == 0) ltagLDS = a;
        }
        __syncthreads();

        // ---- backtrace (serial chain through LDS) ----
        if (tid == 0) {
            int tg = ltagLDS;
            for (int t = T_ - 1; t >= 1; --t) {
                decLDS[t] = (unsigned char)tg;
                if (t < len) tg = bpLDS[t * K_ + tg];  // identity bp for t >= len
            }
            decLDS[0] = (unsigned char)tg;
        }
        __syncthreads();

        // ---- decoded write + accuracy count, 2 t per thread ----
        {
            int good = 0;
            #pragma unroll
            for (int h = 0; h < 2; ++h) {
                int t = tid + h * 256;
                int dv = decLDS[t];
                out[1 + b * T_ + t] = (float)dv;
                good += (t < len && tagB[t] == dv) ? 1 : 0;
            }
            #pragma unroll
            for (int m = 1; m < 64; m <<= 1) good += __shfl_xor(good, m);
            if ((tid & 63) == 0) redILDS[tid >> 6] = good;
        }
        __syncthreads();

        if (tid == 0)
            ws_cnt[b] = redILDS[0] + redILDS[1] + redILDS[2] + redILDS[3];
    }
}

// Final reduction: loss = -mean(ll), accuracy = sum(correct)/sum(len)
__global__ void crf_final(const float* __restrict__ ws_ll,
                          const int* __restrict__ ws_cnt,
                          const int* __restrict__ lengths,
                          float* __restrict__ out)
{
    __shared__ float sll[4];
    __shared__ int scnt[4], slen[4];
    int tid = threadIdx.x;                            // blockDim == B_ == 256
    float ll = ws_ll[tid];
    int   cn = ws_cnt[tid];
    int   L  = lengths[tid];
    #pragma unroll
    for (int m = 1; m < 64; m <<= 1) {
        ll += __shfl_xor(ll, m);
        cn += __shfl_xor(cn, m);
        L  += __shfl_xor(L, m);
    }
    if ((tid & 63) == 0) { sll[tid >> 6] = ll; scnt[tid >> 6] = cn; slen[tid >> 6] = L; }
    __syncthreads();
    if (tid == 0) {
        float llS = sll[0] + sll[1] + sll[2] + sll[3];
        int   cS  = scnt[0] + scnt[1] + scnt[2] + scnt[3];
        int   LS  = slen[0] + slen[1] + slen[2] + slen[3];
        out[0] = -llS / (float)B_;
        out[1 + B_ * T_] = (float)cS / (float)LS;
    }
}

extern "C" void kernel_launch(void* const* d_in, const int* in_sizes, int n_in,
                              void* d_out, int out_size, void* d_ws, size_t ws_size,
                              hipStream_t stream) {
    const float* emissions   = (const float*)d_in[0];
    const int*   tag_ids     = (const int*)d_in[1];
    const int*   lengths     = (const int*)d_in[2];
    const float* transitions = (const float*)d_in[3];
    float* out = (float*)d_out;

    float* ws_ll  = (float*)d_ws;
    int*   ws_cnt = (int*)((char*)d_ws + B_ * sizeof(float));

    crf_main<<<2 * B_, 256, 0, stream>>>(emissions, tag_ids, lengths, transitions,
                                         out, ws_ll, ws_cnt);
    crf_final<<<1, B_, 0, stream>>>(ws_ll, ws_cnt, lengths, out);
}

// Round 12
// 575.045 us; speedup vs baseline: 1.2530x; 1.2530x over previous
//
#include <hip/hip_runtime.h>

#define T_ 512
#define K_ 128
#define B_ 256
#define PADH 68      // dword stride between i-halves (64 + 4 skew, 16B-aligned)

// Role-split grid: blocks [0,256) = forward, blocks [256,512) = viterbi.
// History: 697 (R5 fused 8-wave) -> 548 (R8 role-split) -> 494.6 (R10
// bank-skew + tournament) -> 658 (R11 C=2 restructure, REVERTED: extra
// dependent shfl levels + redundant transcendentals beat the b128 saving;
// kernel is latency/issue-bound, not DS-throughput-bound).
// R12 on the R10 base:
//  (a) vit block handles seq (b+128)&255: under round-robin dispatch,
//      blocks k and k+256 co-locate on a CU; decorrelating lengths means
//      the critical (len~511) block's partner finishes early -> less SIMD
//      issue contention on the kernel-critical CU.
//  (b) hot-loop barrier = s_waitcnt lgkmcnt(0) + raw s_barrier (no vmcnt
//      drain) so the emission prefetch stays in flight across the barrier.

#define ROLE_BARRIER() do {                                         \
    asm volatile("s_waitcnt lgkmcnt(0)" ::: "memory");              \
    __builtin_amdgcn_s_barrier();                                   \
    asm volatile("" ::: "memory");                                  \
} while (0)

__global__ __launch_bounds__(256, 2) void crf_main(
    const float* __restrict__ emissions,
    const int* __restrict__ tag_ids,
    const int* __restrict__ lengths,
    const float* __restrict__ transitions,
    float* __restrict__ out,
    float* __restrict__ ws_ll,
    int* __restrict__ ws_cnt)
{
    const int bid = blockIdx.x;
    const int tid = threadIdx.x;

    if (bid < B_) {
        // ==================== FORWARD block ====================
        __shared__ __align__(16) float eaBuf[2][2 * PADH]; // exp(alpha-S), skewed dbuf
        __shared__ __align__(16) float wmax[4];            // per-wave max of alpha
        __shared__ float redLDS[4];                        // score partials

        const int b   = bid;
        const int len = lengths[b];
        const float* emB = emissions + (size_t)b * T_ * K_;
        const int*  tagB = tag_ids + b * T_;

        // ---- sequence score (unary + binary), 2 t per thread ----
        {
            float s = 0.f;
            #pragma unroll
            for (int h = 0; h < 2; ++h) {
                int t = tid + h * 256;
                if (t < len) {
                    int tg = tagB[t];
                    float v = emB[t * K_ + tg];
                    if (t >= 1) v += transitions[tagB[t - 1] * K_ + tg];
                    s += v;
                }
            }
            #pragma unroll
            for (int m = 1; m < 64; m <<= 1) s += __shfl_xor(s, m);
            if ((tid & 63) == 0) redLDS[tid >> 6] = s;
        }

        const int j = tid >> 1;
        const int c = tid & 1;
        const int wiA = (j >> 6) * PADH + (j & 63);        // skewed write index

        float tbl[64];
        #pragma unroll
        for (int k = 0; k < 64; ++k)
            tbl[k] = __expf(transitions[(c * 64 + k) * K_ + j]);

        // ---- init t = 0 (offset S0 = 0) ----
        {
            float e0 = emB[j];
            if (c == 0) eaBuf[0][wiA] = __expf(e0);
            float wm = e0;
            #pragma unroll
            for (int m = 1; m < 64; m <<= 1) wm = fmaxf(wm, __shfl_xor(wm, m));
            if ((tid & 63) == 0) wmax[tid >> 6] = wm;
        }
        __syncthreads();

        int cur = 0;
        float Sr = 0.f;                                // scale of current ea buffer
        float emN = emB[K_ + j];                       // prefetch t = 1

        for (int t = 1; t < len; ++t) {
            float emC = emN;
            int tn = (t + 1 < T_) ? (t + 1) : t;
            emN = emB[tn * K_ + j];                    // issue early, consume next step

            float Sw;
            if (((t - 1) & 3) == 0) {                  // window start: fresh scale
                float4 wv = *(const float4*)&wmax[0];
                Sw = fmaxf(fmaxf(wv.x, wv.y), fmaxf(wv.z, wv.w));
            } else Sw = Sr;

            const float* ea = &eaBuf[cur][c * PADH];
            float a0 = 0.f, a1 = 0.f, a2 = 0.f, a3 = 0.f;
            #pragma unroll
            for (int k = 0; k < 16; ++k) {
                float4 e4 = *(const float4*)(ea + 4 * k);
                a0 = fmaf(e4.x, tbl[4 * k + 0], a0);
                a1 = fmaf(e4.y, tbl[4 * k + 1], a1);
                a2 = fmaf(e4.z, tbl[4 * k + 2], a2);
                a3 = fmaf(e4.w, tbl[4 * k + 3], a3);
            }
            float dot = (a0 + a1) + (a2 + a3);
            dot += __shfl_xor(dot, 1);                 // combine the two i-halves

            float an = __logf(dot) + Sr + emC;
            if (c == 0) eaBuf[cur ^ 1][wiA] = __expf(an - Sw);
            Sr = Sw;

            if (((t - 1) & 3) == 3) {                  // window end: publish max
                float wm = an;
                #pragma unroll
                for (int m = 1; m < 64; m <<= 1) wm = fmaxf(wm, __shfl_xor(wm, m));
                if ((tid & 63) == 0) wmax[tid >> 6] = wm;
            }
            cur ^= 1;
            ROLE_BARRIER();
        }

        // ---- logZ + final write ----
        float logZv = 0.f;
        if (tid < 64) {
            float s = eaBuf[cur][tid] + eaBuf[cur][PADH + tid];
            #pragma unroll
            for (int m = 1; m < 64; m <<= 1) s += __shfl_xor(s, m);
            logZv = Sr + __logf(s);                    // valid in tid 0
        }
        if (tid == 0) {
            float sc = redLDS[0] + redLDS[1] + redLDS[2] + redLDS[3];
            ws_ll[b] = sc - logZv;
        }

    } else {
        // ==================== VITERBI block ====================
        __shared__ unsigned char bpLDS[T_ * K_];           // 64 KB backpointers
        __shared__ __align__(16) float vaBuf[2][2 * PADH]; // skewed dbuf
        __shared__ unsigned char decLDS[T_];               // decoded chain
        __shared__ int redILDS[4];                         // accuracy partials
        __shared__ int ltagLDS;

        // length-decorrelated pairing: the co-resident fwd block (same CU
        // under RR dispatch) handles seq bid-256; we handle a different one.
        const int b   = ((bid - B_) + 128) & 255;
        const int len = lengths[b];
        const float* emB = emissions + (size_t)b * T_ * K_;
        const int*  tagB = tag_ids + b * T_;

        const int j = tid >> 1;
        const int c = tid & 1;
        const int wiA = (j >> 6) * PADH + (j & 63);

        float tbl[64];
        #pragma unroll
        for (int k = 0; k < 64; ++k)
            tbl[k] = transitions[(c * 64 + k) * K_ + j];

        // ---- init t = 0 ----
        {
            float e0 = emB[j];
            if (c == 0) vaBuf[0][wiA] = e0;
        }
        __syncthreads();

        int cur = 0;
        float emN = emB[K_ + j];                       // prefetch t = 1

        for (int t = 1; t < len; ++t) {
            float emC = emN;
            int tn = (t + 1 < T_) ? (t + 1) : t;
            emN = emB[tn * K_ + j];

            const float* va = &vaBuf[cur][c * PADH];
            // tournament argmax: 16 independent group winners, then 4-level
            // tree; "take right only if strictly greater" at every level ==
            // lowest-index-among-maxima == first-max-wins.
            float v0[16];
            int   g0[16];
            #pragma unroll
            for (int k = 0; k < 16; ++k) {
                float4 v4 = *(const float4*)(va + 4 * k);
                float s0 = v4.x + tbl[4 * k + 0];
                float s1 = v4.y + tbl[4 * k + 1];
                float s2 = v4.z + tbl[4 * k + 2];
                float s3 = v4.w + tbl[4 * k + 3];
                float mA; int aA;
                if (s1 > s0) { mA = s1; aA = 4 * k + 1; } else { mA = s0; aA = 4 * k + 0; }
                float mC; int aC;
                if (s3 > s2) { mC = s3; aC = 4 * k + 3; } else { mC = s2; aC = 4 * k + 2; }
                if (mC > mA) { v0[k] = mC; g0[k] = aC; } else { v0[k] = mA; g0[k] = aA; }
            }
            #pragma unroll
            for (int st = 1; st < 16; st <<= 1) {
                #pragma unroll
                for (int k = 0; k < 16; k += 2 * st) {
                    if (v0[k + st] > v0[k]) { v0[k] = v0[k + st]; g0[k] = g0[k + st]; }
                }
            }
            float mB = v0[0];
            int  arg = g0[0] + c * 64;

            float om = __shfl_xor(mB, 1);
            int   oa = __shfl_xor(arg, 1);
            // low-i half wins ties
            float mLow  = c ? om : mB;   int aLow  = c ? oa : arg;
            float mHigh = c ? mB : om;   int aHigh = c ? arg : oa;
            float mF; int aF;
            if (mHigh > mLow) { mF = mHigh; aF = aHigh; } else { mF = mLow; aF = aLow; }
            if (c == 0) {
                vaBuf[cur ^ 1][wiA] = mF + emC;
                bpLDS[t * K_ + j] = (unsigned char)aF;
            }
            cur ^= 1;
            ROLE_BARRIER();
        }

        // ---- last tag: argmax_j v_final (first-max-wins) ----
        if (tid < 64) {
            int l = tid;
            float m = vaBuf[cur][l]; int a = l;
            float v2 = vaBuf[cur][PADH + l];
            if (v2 > m) { m = v2; a = l + 64; }
            #pragma unroll
            for (int sft = 1; sft < 64; sft <<= 1) {
                float om = __shfl_xor(m, sft);
                int   oa = __shfl_xor(a, sft);
                if (om > m || (om == m && oa < a)) { m = om; a = oa; }
            }
            if (l == 0) ltagLDS = a;
        }
        __syncthreads();

        // ---- backtrace (serial chain through LDS) ----
        if (tid == 0) {
            int tg = ltagLDS;
            for (int t = T_ - 1; t >= 1; --t) {
                decLDS[t] = (unsigned char)tg;
                if (t < len) tg = bpLDS[t * K_ + tg];  // identity bp for t >= len
            }
            decLDS[0] = (unsigned char)tg;
        }
        __syncthreads();

        // ---- decoded write + accuracy count, 2 t per thread ----
        {
            int good = 0;
            #pragma unroll
            for (int h = 0; h < 2; ++h) {
                int t = tid + h * 256;
                int dv = decLDS[t];
                out[1 + b * T_ + t] = (float)dv;
                good += (t < len && tagB[t] == dv) ? 1 : 0;
            }
            #pragma unroll
            for (int m = 1; m < 64; m <<= 1) good += __shfl_xor(good, m);
            if ((tid & 63) == 0) redILDS[tid >> 6] = good;
        }
        __syncthreads();

        if (tid == 0)
            ws_cnt[b] = redILDS[0] + redILDS[1] + redILDS[2] + redILDS[3];
    }
}

// Final reduction: loss = -mean(ll), accuracy = sum(correct)/sum(len)
__global__ void crf_final(const float* __restrict__ ws_ll,
                          const int* __restrict__ ws_cnt,
                          const int* __restrict__ lengths,
                          float* __restrict__ out)
{
    __shared__ float sll[4];
    __shared__ int scnt[4], slen[4];
    int tid = threadIdx.x;                            // blockDim == B_ == 256
    float ll = ws_ll[tid];
    int   cn = ws_cnt[tid];
    int   L  = lengths[tid];
    #pragma unroll
    for (int m = 1; m < 64; m <<= 1) {
        ll += __shfl_xor(ll, m);
        cn += __shfl_xor(cn, m);
        L  += __shfl_xor(L, m);
    }
    if ((tid & 63) == 0) { sll[tid >> 6] = ll; scnt[tid >> 6] = cn; slen[tid >> 6] = L; }
    __syncthreads();
    if (tid == 0) {
        float llS = sll[0] + sll[1] + sll[2] + sll[3];
        int   cS  = scnt[0] + scnt[1] + scnt[2] + scnt[3];
        int   LS  = slen[0] + slen[1] + slen[2] + slen[3];
        out[0] = -llS / (float)B_;
        out[1 + B_ * T_] = (float)cS / (float)LS;
    }
}

extern "C" void kernel_launch(void* const* d_in, const int* in_sizes, int n_in,
                              void* d_out, int out_size, void* d_ws, size_t ws_size,
                              hipStream_t stream) {
    const float* emissions   = (const float*)d_in[0];
    const int*   tag_ids     = (const int*)d_in[1];
    const int*   lengths     = (const int*)d_in[2];
    const float* transitions = (const float*)d_in[3];
    float* out = (float*)d_out;

    float* ws_ll  = (float*)d_ws;
    int*   ws_cnt = (int*)((char*)d_ws + B_ * sizeof(float));

    crf_main<<<2 * B_, 256, 0, stream>>>(emissions, tag_ids, lengths, transitions,
                                         out, ws_ll, ws_cnt);
    crf_final<<<1, B_, 0, stream>>>(ws_ll, ws_cnt, lengths, out);
}